// Round 7
// baseline (426.818 us; speedup 1.0000x reference)
//
#include <hip/hip_runtime.h>
#include <hip/hip_bf16.h>

typedef __bf16 bf16x8 __attribute__((ext_vector_type(8)));
typedef float floatx4 __attribute__((ext_vector_type(4)));

constexpr int Dm = 1024;
constexpr int Hh = 16;
constexpr int HD = 64;
constexpr int FF = 4096;
constexpr int Tt = 2048;
constexpr int Bb = 2;
constexpr int MR = Bb * Tt;  // 4096 rows

typedef const __attribute__((address_space(1))) void* gas1p;
typedef __attribute__((address_space(3))) void* las3p;

// ---------------- transpose + cast fp32 -> bf16 ----------------
__global__ __launch_bounds__(256) void transpose_bf16_kernel(
    const float* __restrict__ W, __hip_bfloat16* __restrict__ WT, int K, int N) {
  __shared__ float tile[32][33];
  int n0 = blockIdx.x * 32, k0 = blockIdx.y * 32;
  int tx = threadIdx.x, ty = threadIdx.y;  // block (32,8)
#pragma unroll
  for (int i = 0; i < 4; ++i) {
    int k = k0 + ty + i * 8;
    tile[ty + i * 8][tx] = W[(size_t)k * N + n0 + tx];
  }
  __syncthreads();
#pragma unroll
  for (int i = 0; i < 4; ++i) {
    int n = n0 + ty + i * 8;
    WT[(size_t)n * K + k0 + tx] = __float2bfloat16(tile[tx][ty + i * 8]);
  }
}

// ---------------- LayerNorm (fp32 in, bf16 out) ----------------
__global__ __launch_bounds__(256) void ln_bf16_kernel(
    const float* __restrict__ x, const float* __restrict__ alpha,
    const float* __restrict__ shift, __hip_bfloat16* __restrict__ out) {
  int row = blockIdx.x;
  const float4 v = ((const float4*)(x + (size_t)row * Dm))[threadIdx.x];
  float s = v.x + v.y + v.z + v.w;
  float ss = v.x * v.x + v.y * v.y + v.z * v.z + v.w * v.w;
#pragma unroll
  for (int o = 32; o; o >>= 1) {
    s += __shfl_down(s, o);
    ss += __shfl_down(ss, o);
  }
  __shared__ float rs[4], rss[4];
  int w = threadIdx.x >> 6, lane = threadIdx.x & 63;
  if (lane == 0) { rs[w] = s; rss[w] = ss; }
  __syncthreads();
  float tot = rs[0] + rs[1] + rs[2] + rs[3];
  float tots = rss[0] + rss[1] + rss[2] + rss[3];
  float mean = tot * (1.f / Dm);
  float var = tots * (1.f / Dm) - mean * mean;
  float rstd = rsqrtf(var + 1e-5f);
  int col = threadIdx.x * 4;
  __hip_bfloat16* op = out + (size_t)row * Dm + col;
  float vv[4] = {v.x, v.y, v.z, v.w};
#pragma unroll
  for (int e = 0; e < 4; ++e)
    op[e] = __float2bfloat16((vv[e] - mean) * rstd * alpha[col + e] + shift[col + e]);
}

// ---------------- tiled bf16 MFMA GEMM: C[M,N] = A[M,K] @ BT[N,K]^T ----------
// A: global_load_lds(16B) into 4 LDS buffers (XOR-swizzled).
// B: BYPASSES LDS — per-wave fragments loaded global->VGPR with a depth-2
// register prefetch (4 slots, K-loop unrolled by 4 so slots are static).
// One fused "s_waitcnt vmcnt(2*(ANL+NI)) lgkmcnt(0); s_barrier" per iter:
// tiles k+1/k+2 stay in flight across the barrier, tile-k drained exactly.
template <int EPI, int TM>
__global__ __launch_bounds__(256) void gemm_tiled(
    const __bf16* __restrict__ A, const __bf16* __restrict__ BT,
    void* __restrict__ Cout, const float* __restrict__ bias,
    const float* __restrict__ resid, int M, int N, int K) {
  constexpr int ANL = TM / 64;                 // A-DMA loads per thread per iter
  constexpr int NI = (TM == 128) ? 4 : 2;      // B frags per wave
  constexpr int WN = (TM == 128) ? 64 : 32;    // cols per wave
  __shared__ __bf16 As[4 * TM * 32];
  const int tid = threadIdx.x;
  const int w = tid >> 6, lane = tid & 63;
  const int r16 = lane & 15, quad = lane >> 4;
  const int wm = (TM == 128) ? (w & 1) : 0;
  const int wn = (TM == 128) ? (w >> 1) : w;
  const int m0 = blockIdx.y * TM;
  const int n0 = blockIdx.x * 128;

  int sa_row[ANL], sa_gcb[ANL];
#pragma unroll
  for (int p = 0; p < ANL; ++p) {
    int idx = tid + p * 256;
    sa_row[p] = idx >> 2;
    sa_gcb[p] = (idx & 3) ^ ((sa_row[p] >> 1) & 3);
  }

  int aoffL[4];
#pragma unroll
  for (int i = 0; i < 4; ++i) {
    int ra = wm * 64 + i * 16 + r16;
    aoffL[i] = ra * 32 + (quad ^ ((ra >> 1) & 3)) * 8;
  }

  // per-lane B row pointers (k-invariant part)
  const __bf16* bp[NI];
#pragma unroll
  for (int i = 0; i < NI; ++i)
    bp[i] = BT + (size_t)(n0 + wn * WN + i * 16 + r16) * K + quad * 8;

  bf16x8 breg[4][NI];
  floatx4 acc[4][NI] = {};

  auto stageA = [&](int kt, int buf) {
    int k0 = kt * 32;
#pragma unroll
    for (int p = 0; p < ANL; ++p)
      __builtin_amdgcn_global_load_lds(
          (gas1p)(A + (size_t)(m0 + sa_row[p]) * K + k0 + sa_gcb[p] * 8),
          (las3p)(&As[buf * TM * 32 + (tid + p * 256) * 8]), 16, 0, 0);
  };
  auto loadB = [&](int kt, bf16x8 (&dst)[NI]) {
#pragma unroll
    for (int i = 0; i < NI; ++i)
      dst[i] = *reinterpret_cast<const bf16x8*>(bp[i] + kt * 32);
  };
  auto wait2 = [&]() {
    if constexpr (TM == 128)
      asm volatile("s_waitcnt vmcnt(12) lgkmcnt(0)\n\ts_barrier" ::: "memory");
    else
      asm volatile("s_waitcnt vmcnt(6) lgkmcnt(0)\n\ts_barrier" ::: "memory");
  };
  auto wait1 = [&]() {
    if constexpr (TM == 128)
      asm volatile("s_waitcnt vmcnt(6) lgkmcnt(0)\n\ts_barrier" ::: "memory");
    else
      asm volatile("s_waitcnt vmcnt(3) lgkmcnt(0)\n\ts_barrier" ::: "memory");
  };
  auto wait0 = [&]() {
    asm volatile("s_waitcnt vmcnt(0) lgkmcnt(0)\n\ts_barrier" ::: "memory");
  };
  auto compute = [&](int buf, bf16x8 (&bc)[NI]) {
    bf16x8 a[4];
#pragma unroll
    for (int i = 0; i < 4; ++i)
      a[i] = *reinterpret_cast<const bf16x8*>(&As[buf * TM * 32 + aoffL[i]]);
#pragma unroll
    for (int mi = 0; mi < 4; ++mi)
#pragma unroll
      for (int ni = 0; ni < NI; ++ni)
        acc[mi][ni] = __builtin_amdgcn_mfma_f32_16x16x32_bf16(a[mi], bc[ni], acc[mi][ni], 0, 0, 0);
  };

  const int nk = K / 32;  // nk % 4 == 0, nk >= 32
  stageA(0, 0); loadB(0, breg[0]);
  stageA(1, 1); loadB(1, breg[1]);
  for (int kt = 0; kt + 4 < nk; kt += 4) {
    stageA(kt + 2, 2); loadB(kt + 2, breg[2]); wait2(); compute(0, breg[0]);
    stageA(kt + 3, 3); loadB(kt + 3, breg[3]); wait2(); compute(1, breg[1]);
    stageA(kt + 4, 0); loadB(kt + 4, breg[0]); wait2(); compute(2, breg[2]);
    stageA(kt + 5, 1); loadB(kt + 5, breg[1]); wait2(); compute(3, breg[3]);
  }
  {
    int kt = nk - 4;  // buffers (nk-4)&3 == 0
    stageA(kt + 2, 2); loadB(kt + 2, breg[2]); wait2(); compute(0, breg[0]);
    stageA(kt + 3, 3); loadB(kt + 3, breg[3]); wait2(); compute(1, breg[1]);
    wait1(); compute(2, breg[2]);
    wait0(); compute(3, breg[3]);
  }

#pragma unroll
  for (int mi = 0; mi < 4; ++mi)
#pragma unroll
    for (int ni = 0; ni < NI; ++ni)
#pragma unroll
      for (int r = 0; r < 4; ++r) {
        int row = m0 + wm * 64 + mi * 16 + quad * 4 + r;
        int col = n0 + wn * WN + ni * 16 + r16;
        float vacc = acc[mi][ni][r];
        if (EPI == 1) {
          vacc += bias[col] + resid[(size_t)row * N + col];
          ((float*)Cout)[(size_t)row * N + col] = vacc;
        } else if (EPI == 2) {
          vacc += bias[col];
          float u = vacc + 0.044715f * vacc * vacc * vacc;
          float e = __builtin_amdgcn_exp2f(2.3025851f * u);
          float th = 1.f - 2.f * __builtin_amdgcn_rcpf(e + 1.f);
          ((__hip_bfloat16*)Cout)[(size_t)row * N + col] =
              __float2bfloat16(0.5f * vacc * (1.f + th));
        } else {  // EPI 3: fused QKV -> head-major [3][B,H,T,64]
          int bb = row >> 11, t = row & 2047;
          int qkv = col >> 10, rem = col & 1023;
          int h = rem >> 6, d = rem & 63;
          ((__hip_bfloat16*)Cout)[(size_t)qkv * (MR * Dm) +
                                  ((size_t)(bb * Hh + h) * Tt + t) * HD + d] =
              __float2bfloat16(vacc);
        }
      }
}

// ---------------- V transpose: [B,H,T,64] -> [B*H,64,T] ----------------
__global__ __launch_bounds__(256) void vtrans_kernel(
    const __bf16* __restrict__ vin, __bf16* __restrict__ vout) {
  __shared__ __bf16 tile[64][72];
  int bh = blockIdx.x, t0 = blockIdx.y * 64;
  int tid = threadIdx.x;
#pragma unroll
  for (int p = 0; p < 2; ++p) {
    int idx = tid + p * 256;
    int r = idx >> 3, c = (idx & 7) * 8;
    *reinterpret_cast<bf16x8*>(&tile[r][c]) =
        *reinterpret_cast<const bf16x8*>(vin + ((size_t)bh * Tt + t0 + r) * HD + c);
  }
  __syncthreads();
#pragma unroll
  for (int p = 0; p < 2; ++p) {
    int idx = tid + p * 256;
    int d = idx >> 3, c = (idx & 7) * 8;
    bf16x8 v;
#pragma unroll
    for (int j = 0; j < 8; ++j) v[j] = tile[c + j][d];
    *reinterpret_cast<bf16x8*>(vout + ((size_t)bh * HD + d) * Tt + t0 + c) = v;
  }
}

// ---------------- MFMA flash attention, fixed-max softmax ----------------
__global__ __launch_bounds__(256) void attn_kernel(
    const __bf16* __restrict__ qp, const __bf16* __restrict__ kp,
    const __bf16* __restrict__ vtp, __bf16* __restrict__ ctx) {
  __shared__ __bf16 Ks[2][64 * 64];   // [kcol][d], swizzled chunks
  __shared__ __bf16 Vt[2][80 * 64];   // [d][kcol]; rows 64..79: ones/zeros
  __shared__ __bf16 Ps[4 * 16 * 72];  // per-wave P [qrow][kcol]
  int bh = blockIdx.x;
  int b = bh >> 4, h = bh & 15;
  int qt = 31 - blockIdx.y;  // longest blocks first
  int tid = threadIdx.x;
  int w = tid >> 6, lane = tid & 63;
  int r16 = lane & 15, quad = lane >> 4;
  int q0 = qt * 64;
  const size_t base = (size_t)bh * Tt * HD;

  {
    int r = 64 + (tid >> 4);
    int c = (tid & 15) * 4;
    __bf16 val = (r == 64) ? (__bf16)1.0f : (__bf16)0.0f;
#pragma unroll
    for (int bu = 0; bu < 2; ++bu) {
      __bf16* p = &Vt[bu][r * 64 + c];
      p[0] = val; p[1] = val; p[2] = val; p[3] = val;
    }
  }

  const float QS = 0.125f * 1.44269504088896f;
  bf16x8 aq[2];
#pragma unroll
  for (int ks = 0; ks < 2; ++ks) {
    bf16x8 t = *reinterpret_cast<const bf16x8*>(
        qp + base + (size_t)(q0 + w * 16 + r16) * HD + ks * 32 + quad * 8);
#pragma unroll
    for (int j = 0; j < 8; ++j) t[j] = (__bf16)((float)t[j] * QS);
    aq[ks] = t;
  }

  auto stage = [&](int kt, int buf) {
#pragma unroll
    for (int p = 0; p < 2; ++p) {
      int idx = tid + p * 256;
      int row = idx >> 3, c = idx & 7;
      int gc = c ^ (row & 7);
      __builtin_amdgcn_global_load_lds(
          (gas1p)(kp + base + (size_t)(kt * 64 + row) * HD + gc * 8),
          (las3p)(&Ks[buf][idx * 8]), 16, 0, 0);
      __builtin_amdgcn_global_load_lds(
          (gas1p)(vtp + base + (size_t)row * Tt + kt * 64 + gc * 8),
          (las3p)(&Vt[buf][idx * 8]), 16, 0, 0);
    }
  };

  floatx4 O[5] = {};
  stage(0, 0);
  for (int kt = 0; kt <= qt; ++kt) {
    int cur = kt & 1;
    __syncthreads();
    if (kt < qt) stage(kt + 1, cur ^ 1);

    floatx4 sacc[4] = {};
#pragma unroll
    for (int ks = 0; ks < 2; ++ks)
#pragma unroll
      for (int ni = 0; ni < 4; ++ni) {
        int row = ni * 16 + r16;
        bf16x8 bk = *reinterpret_cast<const bf16x8*>(
            &Ks[cur][row * 64 + (((ks << 2) | quad) ^ (r16 & 7)) * 8]);
        sacc[ni] = __builtin_amdgcn_mfma_f32_16x16x32_bf16(aq[ks], bk, sacc[ni], 0, 0, 0);
      }

    bool diag = (kt == qt);
#pragma unroll
    for (int ni = 0; ni < 4; ++ni)
#pragma unroll
      for (int r = 0; r < 4; ++r) {
        float sv = sacc[ni][r];
        if (diag)
          sv = (ni * 16 + r16 <= w * 16 + quad * 4 + r) ? sv : -__builtin_inff();
        Ps[w * 1152 + (quad * 4 + r) * 72 + ni * 16 + r16] =
            (__bf16)__builtin_amdgcn_exp2f(sv);
      }

#pragma unroll
    for (int ks = 0; ks < 2; ++ks) {
      bf16x8 ap = *reinterpret_cast<const bf16x8*>(
          &Ps[w * 1152 + r16 * 72 + ks * 32 + quad * 8]);
#pragma unroll
      for (int ni = 0; ni < 5; ++ni) {
        int row = ni * 16 + r16;
        bf16x8 bv = *reinterpret_cast<const bf16x8*>(
            &Vt[cur][row * 64 + (((ks << 2) | quad) ^ (r16 & 7)) * 8]);
        O[ni] = __builtin_amdgcn_mfma_f32_16x16x32_bf16(ap, bv, O[ni], 0, 0, 0);
      }
    }
  }

  float invl[4];
#pragma unroll
  for (int r = 0; r < 4; ++r) {
    float l = __shfl(O[4][r], lane & 48);
    invl[r] = 1.f / l;
  }
#pragma unroll
  for (int r = 0; r < 4; ++r) {
    int qrow = q0 + w * 16 + quad * 4 + r;
    __bf16* op = ctx + ((size_t)(b * Tt + qrow)) * Dm + h * HD;
#pragma unroll
    for (int ni = 0; ni < 4; ++ni)
      op[ni * 16 + r16] = (__bf16)(O[ni][r] * invl[r]);
  }
}

extern "C" void kernel_launch(void* const* d_in, const int* in_sizes, int n_in,
                              void* d_out, int out_size, void* d_ws, size_t ws_size,
                              hipStream_t stream) {
  const float* x = (const float*)d_in[0];
  const float* wq = (const float*)d_in[1];
  const float* wk = (const float*)d_in[2];
  const float* wv = (const float*)d_in[3];
  const float* wo = (const float*)d_in[4];
  const float* bo = (const float*)d_in[5];
  const float* w1 = (const float*)d_in[6];
  const float* b1 = (const float*)d_in[7];
  const float* w2 = (const float*)d_in[8];
  const float* b2 = (const float*)d_in[9];
  const float* a1 = (const float*)d_in[10];
  const float* s1 = (const float*)d_in[11];
  const float* a2 = (const float*)d_in[12];
  const float* s2 = (const float*)d_in[13];
  float* out = (float*)d_out;
  char* ws = (char*)d_ws;

  const size_t MB = 1024 * 1024;
  __hip_bfloat16* WqkvT = (__hip_bfloat16*)(ws + 0 * MB);  // 6MB: WqT|WkT|WvT
  __hip_bfloat16* WkT = (__hip_bfloat16*)(ws + 2 * MB);
  __hip_bfloat16* WvT = (__hip_bfloat16*)(ws + 4 * MB);
  __hip_bfloat16* WoT = (__hip_bfloat16*)(ws + 6 * MB);
  __hip_bfloat16* W1T = (__hip_bfloat16*)(ws + 8 * MB);
  __hip_bfloat16* W2T = (__hip_bfloat16*)(ws + 16 * MB);
  __hip_bfloat16* h1  = (__hip_bfloat16*)(ws + 24 * MB);
  __hip_bfloat16* qkvb = (__hip_bfloat16*)(ws + 32 * MB);  // 24MB: q|k|v head-major
  __hip_bfloat16* ctxb = (__hip_bfloat16*)(ws + 56 * MB);  // token-major
  __hip_bfloat16* h2  = (__hip_bfloat16*)(ws + 64 * MB);
  __hip_bfloat16* g   = (__hip_bfloat16*)(ws + 72 * MB);   // 32MB
  __hip_bfloat16* vtb = (__hip_bfloat16*)(ws + 104 * MB);  // 8MB: V^T [B*H,64,T]

  dim3 tb(32, 8);
  transpose_bf16_kernel<<<dim3(Dm / 32, Dm / 32), tb, 0, stream>>>(wq, WqkvT, Dm, Dm);
  transpose_bf16_kernel<<<dim3(Dm / 32, Dm / 32), tb, 0, stream>>>(wk, WkT, Dm, Dm);
  transpose_bf16_kernel<<<dim3(Dm / 32, Dm / 32), tb, 0, stream>>>(wv, WvT, Dm, Dm);
  transpose_bf16_kernel<<<dim3(Dm / 32, Dm / 32), tb, 0, stream>>>(wo, WoT, Dm, Dm);
  transpose_bf16_kernel<<<dim3(FF / 32, Dm / 32), tb, 0, stream>>>(w1, W1T, Dm, FF);
  transpose_bf16_kernel<<<dim3(Dm / 32, FF / 32), tb, 0, stream>>>(w2, W2T, FF, Dm);

  ln_bf16_kernel<<<MR, 256, 0, stream>>>(x, a1, s1, h1);

  gemm_tiled<3, 128><<<dim3(3 * Dm / 128, MR / 128), 256, 0, stream>>>(
      (const __bf16*)h1, (const __bf16*)WqkvT, qkvb, nullptr, nullptr, MR, 3 * Dm, Dm);

  vtrans_kernel<<<dim3(Bb * Hh, Tt / 64), 256, 0, stream>>>(
      (const __bf16*)(qkvb + 2 * (size_t)MR * Dm), (__bf16*)vtb);

  attn_kernel<<<dim3(Bb * Hh, Tt / 64), 256, 0, stream>>>(
      (const __bf16*)qkvb, (const __bf16*)(qkvb + (size_t)MR * Dm),
      (const __bf16*)vtb, (__bf16*)ctxb);

  gemm_tiled<1, 64><<<dim3(Dm / 128, MR / 64), 256, 0, stream>>>(
      (const __bf16*)ctxb, (const __bf16*)WoT, out, bo, x, MR, Dm, Dm);

  ln_bf16_kernel<<<MR, 256, 0, stream>>>(out, a2, s2, h2);

  gemm_tiled<2, 128><<<dim3(FF / 128, MR / 128), 256, 0, stream>>>(
      (const __bf16*)h2, (const __bf16*)W1T, g, b1, nullptr, MR, FF, Dm);

  gemm_tiled<1, 64><<<dim3(Dm / 128, MR / 64), 256, 0, stream>>>(
      (const __bf16*)g, (const __bf16*)W2T, out, b2, out, MR, Dm, FF);
}

// Round 8
// 363.829 us; speedup vs baseline: 1.1731x; 1.1731x over previous
//
#include <hip/hip_runtime.h>
#include <hip/hip_bf16.h>

typedef __bf16 bf16x8 __attribute__((ext_vector_type(8)));
typedef float floatx4 __attribute__((ext_vector_type(4)));

constexpr int Dm = 1024;
constexpr int Hh = 16;
constexpr int HD = 64;
constexpr int FF = 4096;
constexpr int Tt = 2048;
constexpr int Bb = 2;
constexpr int MR = Bb * Tt;  // 4096 rows

typedef const __attribute__((address_space(1))) void* gas1p;
typedef __attribute__((address_space(3))) void* las3p;

// ---------------- transpose + cast fp32 -> bf16 ----------------
__global__ __launch_bounds__(256) void transpose_bf16_kernel(
    const float* __restrict__ W, __hip_bfloat16* __restrict__ WT, int K, int N) {
  __shared__ float tile[32][33];
  int n0 = blockIdx.x * 32, k0 = blockIdx.y * 32;
  int tx = threadIdx.x, ty = threadIdx.y;  // block (32,8)
#pragma unroll
  for (int i = 0; i < 4; ++i) {
    int k = k0 + ty + i * 8;
    tile[ty + i * 8][tx] = W[(size_t)k * N + n0 + tx];
  }
  __syncthreads();
#pragma unroll
  for (int i = 0; i < 4; ++i) {
    int n = n0 + ty + i * 8;
    WT[(size_t)n * K + k0 + tx] = __float2bfloat16(tile[tx][ty + i * 8]);
  }
}

// ---------------- LayerNorm (fp32 in, bf16 out) ----------------
__global__ __launch_bounds__(256) void ln_bf16_kernel(
    const float* __restrict__ x, const float* __restrict__ alpha,
    const float* __restrict__ shift, __hip_bfloat16* __restrict__ out) {
  int row = blockIdx.x;
  const float4 v = ((const float4*)(x + (size_t)row * Dm))[threadIdx.x];
  float s = v.x + v.y + v.z + v.w;
  float ss = v.x * v.x + v.y * v.y + v.z * v.z + v.w * v.w;
#pragma unroll
  for (int o = 32; o; o >>= 1) {
    s += __shfl_down(s, o);
    ss += __shfl_down(ss, o);
  }
  __shared__ float rs[4], rss[4];
  int w = threadIdx.x >> 6, lane = threadIdx.x & 63;
  if (lane == 0) { rs[w] = s; rss[w] = ss; }
  __syncthreads();
  float tot = rs[0] + rs[1] + rs[2] + rs[3];
  float tots = rss[0] + rss[1] + rss[2] + rss[3];
  float mean = tot * (1.f / Dm);
  float var = tots * (1.f / Dm) - mean * mean;
  float rstd = rsqrtf(var + 1e-5f);
  int col = threadIdx.x * 4;
  __hip_bfloat16* op = out + (size_t)row * Dm + col;
  float vv[4] = {v.x, v.y, v.z, v.w};
#pragma unroll
  for (int e = 0; e < 4; ++e)
    op[e] = __float2bfloat16((vv[e] - mean) * rstd * alpha[col + e] + shift[col + e]);
}

// ------------- TM=128 GEMM (round-6 proven): 3 LDS buffers, depth-2 --------
// EPI 2: +bias[col], GELU, store bf16.
// EPI 3: fused-QKV scatter: col selects q/k/v and head; store bf16 head-major.
template <int EPI>
__global__ __launch_bounds__(256) void gemm_tiled(
    const __bf16* __restrict__ A, const __bf16* __restrict__ BT,
    void* __restrict__ Cout, const float* __restrict__ bias,
    const float* __restrict__ resid, int M, int N, int K) {
  __shared__ __bf16 As[3][128 * 32];
  __shared__ __bf16 Bs[3][128 * 32];
  const int tid = threadIdx.x;
  const int w = tid >> 6, lane = tid & 63;
  const int r16 = lane & 15, quad = lane >> 4;
  const int wm = w & 1, wn = w >> 1;
  const int m0 = blockIdx.y * 128;
  const int n0 = blockIdx.x * 128;

  int s_row[2], s_gcb[2];
#pragma unroll
  for (int p = 0; p < 2; ++p) {
    int idx = tid + p * 256;
    s_row[p] = idx >> 2;
    s_gcb[p] = (idx & 3) ^ ((s_row[p] >> 1) & 3);
  }

  int aoffL[4], boffL[4];
#pragma unroll
  for (int i = 0; i < 4; ++i) {
    int ra = wm * 64 + i * 16 + r16;
    aoffL[i] = ra * 32 + (quad ^ ((ra >> 1) & 3)) * 8;
    int rb = wn * 64 + i * 16 + r16;
    boffL[i] = rb * 32 + (quad ^ ((rb >> 1) & 3)) * 8;
  }

  auto stage = [&](int kt, int buf) {
    int k0 = kt * 32;
#pragma unroll
    for (int p = 0; p < 2; ++p) {
      __builtin_amdgcn_global_load_lds(
          (gas1p)(A + (size_t)(m0 + s_row[p]) * K + k0 + s_gcb[p] * 8),
          (las3p)(&As[buf][(tid + p * 256) * 8]), 16, 0, 0);
      __builtin_amdgcn_global_load_lds(
          (gas1p)(BT + (size_t)(n0 + s_row[p]) * K + k0 + s_gcb[p] * 8),
          (las3p)(&Bs[buf][(tid + p * 256) * 8]), 16, 0, 0);
    }
  };

  floatx4 acc[4][4] = {};
  const int nk = K / 32;
  stage(0, 0);
  stage(1, 1);
  for (int kt = 0; kt < nk; ++kt) {
    int cur = kt - (kt / 3) * 3;  // kt % 3
    if (kt + 1 < nk)
      asm volatile("s_waitcnt vmcnt(4) lgkmcnt(0)\n\ts_barrier" ::: "memory");
    else
      asm volatile("s_waitcnt vmcnt(0) lgkmcnt(0)\n\ts_barrier" ::: "memory");
    if (kt + 2 < nk) {
      int nb = kt + 2;
      nb -= (nb / 3) * 3;
      stage(kt + 2, nb);
    }
    bf16x8 a[4], b[4];
#pragma unroll
    for (int i = 0; i < 4; ++i) a[i] = *reinterpret_cast<const bf16x8*>(&As[cur][aoffL[i]]);
#pragma unroll
    for (int i = 0; i < 4; ++i) b[i] = *reinterpret_cast<const bf16x8*>(&Bs[cur][boffL[i]]);
#pragma unroll
    for (int mi = 0; mi < 4; ++mi)
#pragma unroll
      for (int ni = 0; ni < 4; ++ni)
        acc[mi][ni] = __builtin_amdgcn_mfma_f32_16x16x32_bf16(a[mi], b[ni], acc[mi][ni], 0, 0, 0);
  }

#pragma unroll
  for (int mi = 0; mi < 4; ++mi)
#pragma unroll
    for (int ni = 0; ni < 4; ++ni)
#pragma unroll
      for (int r = 0; r < 4; ++r) {
        int row = m0 + wm * 64 + mi * 16 + quad * 4 + r;
        int col = n0 + wn * 64 + ni * 16 + r16;
        float vacc = acc[mi][ni][r];
        if (EPI == 2) {
          vacc += bias[col];
          float u = vacc + 0.044715f * vacc * vacc * vacc;
          float e = __builtin_amdgcn_exp2f(2.3025851f * u);
          float th = 1.f - 2.f * __builtin_amdgcn_rcpf(e + 1.f);
          ((__hip_bfloat16*)Cout)[(size_t)row * N + col] =
              __float2bfloat16(0.5f * vacc * (1.f + th));
        } else {  // EPI 3: fused QKV -> head-major [3][B,H,T,64]
          int bb = row >> 11, t = row & 2047;
          int qkv = col >> 10, rem = col & 1023;
          int h = rem >> 6, d = rem & 63;
          ((__hip_bfloat16*)Cout)[(size_t)qkv * (MR * Dm) +
                                  ((size_t)(bb * Hh + h) * Tt + t) * HD + d] =
              __float2bfloat16(vacc);
        }
      }
}

// ------------- TM=64 GEMM: 4 LDS buffers, depth-3, XCD row-affinity --------
// Grid MUST be (8, M/64). p=by*8+bx; XCD c=p&7 owns rows 8c..8c+7 so each
// A-strip flows through exactly one L2. Steady-state "s_waitcnt vmcnt(6)"
// keeps 2 full tiles (6 loads) in flight across every barrier (~900cyc cover).
// EPI 1: +bias[col]+resid[row*N+col], store fp32.
__global__ __launch_bounds__(256) void gemm_tiled64(
    const __bf16* __restrict__ A, const __bf16* __restrict__ BT,
    float* __restrict__ Cout, const float* __restrict__ bias,
    const float* __restrict__ resid, int M, int N, int K) {
  __shared__ __bf16 As[4][64 * 32];
  __shared__ __bf16 Bs[4][128 * 32];
  const int tid = threadIdx.x;
  const int w = tid >> 6, lane = tid & 63;
  const int r16 = lane & 15, quad = lane >> 4;
  int p = blockIdx.y * 8 + blockIdx.x;
  int c = p & 7, i0 = p >> 3;
  const int m0 = ((c << 3) | (i0 & 7)) * 64;
  const int n0 = (i0 >> 3) * 128;

  // A staging: 256 chunks (ANL=1)
  int sa_row = tid >> 2;
  int sa_gcb = (tid & 3) ^ ((sa_row >> 1) & 3);
  int sb_row[2], sb_gcb[2];
#pragma unroll
  for (int q = 0; q < 2; ++q) {
    int idx = tid + q * 256;
    sb_row[q] = idx >> 2;
    sb_gcb[q] = (idx & 3) ^ ((sb_row[q] >> 1) & 3);
  }

  int aoffL[4], boffL[2];
#pragma unroll
  for (int i = 0; i < 4; ++i) {
    int ra = i * 16 + r16;
    aoffL[i] = ra * 32 + (quad ^ ((ra >> 1) & 3)) * 8;
  }
#pragma unroll
  for (int i = 0; i < 2; ++i) {
    int rb = w * 32 + i * 16 + r16;
    boffL[i] = rb * 32 + (quad ^ ((rb >> 1) & 3)) * 8;
  }

  auto stage = [&](int kt, int buf) {
    int k0 = kt * 32;
    __builtin_amdgcn_global_load_lds(
        (gas1p)(A + (size_t)(m0 + sa_row) * K + k0 + sa_gcb * 8),
        (las3p)(&As[buf][tid * 8]), 16, 0, 0);
#pragma unroll
    for (int q = 0; q < 2; ++q)
      __builtin_amdgcn_global_load_lds(
          (gas1p)(BT + (size_t)(n0 + sb_row[q]) * K + k0 + sb_gcb[q] * 8),
          (las3p)(&Bs[buf][(tid + q * 256) * 8]), 16, 0, 0);
  };

  floatx4 acc[4][2] = {};
  const int nk = K / 32;  // divisible by 4
  stage(0, 0);
  stage(1, 1);
  stage(2, 2);
  for (int kt = 0; kt < nk; ++kt) {
    int cur = kt & 3;
    if (kt + 2 < nk)
      asm volatile("s_waitcnt vmcnt(6) lgkmcnt(0)\n\ts_barrier" ::: "memory");
    else if (kt + 1 < nk)
      asm volatile("s_waitcnt vmcnt(3) lgkmcnt(0)\n\ts_barrier" ::: "memory");
    else
      asm volatile("s_waitcnt vmcnt(0) lgkmcnt(0)\n\ts_barrier" ::: "memory");
    if (kt + 3 < nk) stage(kt + 3, (kt + 3) & 3);
    bf16x8 a[4], b[2];
#pragma unroll
    for (int i = 0; i < 4; ++i) a[i] = *reinterpret_cast<const bf16x8*>(&As[cur][aoffL[i]]);
#pragma unroll
    for (int i = 0; i < 2; ++i) b[i] = *reinterpret_cast<const bf16x8*>(&Bs[cur][boffL[i]]);
#pragma unroll
    for (int mi = 0; mi < 4; ++mi)
#pragma unroll
      for (int ni = 0; ni < 2; ++ni)
        acc[mi][ni] = __builtin_amdgcn_mfma_f32_16x16x32_bf16(a[mi], b[ni], acc[mi][ni], 0, 0, 0);
  }

#pragma unroll
  for (int mi = 0; mi < 4; ++mi)
#pragma unroll
    for (int ni = 0; ni < 2; ++ni)
#pragma unroll
      for (int r = 0; r < 4; ++r) {
        int row = m0 + mi * 16 + quad * 4 + r;
        int col = n0 + w * 32 + ni * 16 + r16;
        float vacc = acc[mi][ni][r] + bias[col] + resid[(size_t)row * N + col];
        Cout[(size_t)row * N + col] = vacc;
      }
}

// ---------------- V transpose: [B,H,T,64] -> [B*H,64,T] ----------------
__global__ __launch_bounds__(256) void vtrans_kernel(
    const __bf16* __restrict__ vin, __bf16* __restrict__ vout) {
  __shared__ __bf16 tile[64][72];
  int bh = blockIdx.x, t0 = blockIdx.y * 64;
  int tid = threadIdx.x;
#pragma unroll
  for (int p = 0; p < 2; ++p) {
    int idx = tid + p * 256;
    int r = idx >> 3, c = (idx & 7) * 8;
    *reinterpret_cast<bf16x8*>(&tile[r][c]) =
        *reinterpret_cast<const bf16x8*>(vin + ((size_t)bh * Tt + t0 + r) * HD + c);
  }
  __syncthreads();
#pragma unroll
  for (int p = 0; p < 2; ++p) {
    int idx = tid + p * 256;
    int d = idx >> 3, c = (idx & 7) * 8;
    bf16x8 v;
#pragma unroll
    for (int j = 0; j < 8; ++j) v[j] = tile[c + j][d];
    *reinterpret_cast<bf16x8*>(vout + ((size_t)bh * HD + d) * Tt + t0 + c) = v;
  }
}

// ---------------- MFMA flash attention, fixed-max softmax ----------------
__global__ __launch_bounds__(256) void attn_kernel(
    const __bf16* __restrict__ qp, const __bf16* __restrict__ kp,
    const __bf16* __restrict__ vtp, __bf16* __restrict__ ctx) {
  __shared__ __bf16 Ks[2][64 * 64];   // [kcol][d], swizzled chunks
  __shared__ __bf16 Vt[2][80 * 64];   // [d][kcol]; rows 64..79: ones/zeros
  __shared__ __bf16 Ps[4 * 16 * 72];  // per-wave P [qrow][kcol]
  int bh = blockIdx.x;
  int b = bh >> 4, h = bh & 15;
  int qt = 31 - blockIdx.y;  // longest blocks first
  int tid = threadIdx.x;
  int w = tid >> 6, lane = tid & 63;
  int r16 = lane & 15, quad = lane >> 4;
  int q0 = qt * 64;
  const size_t base = (size_t)bh * Tt * HD;

  {
    int r = 64 + (tid >> 4);
    int c = (tid & 15) * 4;
    __bf16 val = (r == 64) ? (__bf16)1.0f : (__bf16)0.0f;
#pragma unroll
    for (int bu = 0; bu < 2; ++bu) {
      __bf16* p = &Vt[bu][r * 64 + c];
      p[0] = val; p[1] = val; p[2] = val; p[3] = val;
    }
  }

  const float QS = 0.125f * 1.44269504088896f;
  bf16x8 aq[2];
#pragma unroll
  for (int ks = 0; ks < 2; ++ks) {
    bf16x8 t = *reinterpret_cast<const bf16x8*>(
        qp + base + (size_t)(q0 + w * 16 + r16) * HD + ks * 32 + quad * 8);
#pragma unroll
    for (int j = 0; j < 8; ++j) t[j] = (__bf16)((float)t[j] * QS);
    aq[ks] = t;
  }

  auto stage = [&](int kt, int buf) {
#pragma unroll
    for (int p = 0; p < 2; ++p) {
      int idx = tid + p * 256;
      int row = idx >> 3, c = idx & 7;
      int gc = c ^ (row & 7);
      __builtin_amdgcn_global_load_lds(
          (gas1p)(kp + base + (size_t)(kt * 64 + row) * HD + gc * 8),
          (las3p)(&Ks[buf][idx * 8]), 16, 0, 0);
      __builtin_amdgcn_global_load_lds(
          (gas1p)(vtp + base + (size_t)row * Tt + kt * 64 + gc * 8),
          (las3p)(&Vt[buf][idx * 8]), 16, 0, 0);
    }
  };

  floatx4 O[5] = {};
  stage(0, 0);
  for (int kt = 0; kt <= qt; ++kt) {
    int cur = kt & 1;
    __syncthreads();
    if (kt < qt) stage(kt + 1, cur ^ 1);

    floatx4 sacc[4] = {};
#pragma unroll
    for (int ks = 0; ks < 2; ++ks)
#pragma unroll
      for (int ni = 0; ni < 4; ++ni) {
        int row = ni * 16 + r16;
        bf16x8 bk = *reinterpret_cast<const bf16x8*>(
            &Ks[cur][row * 64 + (((ks << 2) | quad) ^ (r16 & 7)) * 8]);
        sacc[ni] = __builtin_amdgcn_mfma_f32_16x16x32_bf16(aq[ks], bk, sacc[ni], 0, 0, 0);
      }

    bool diag = (kt == qt);
#pragma unroll
    for (int ni = 0; ni < 4; ++ni)
#pragma unroll
      for (int r = 0; r < 4; ++r) {
        float sv = sacc[ni][r];
        if (diag)
          sv = (ni * 16 + r16 <= w * 16 + quad * 4 + r) ? sv : -__builtin_inff();
        Ps[w * 1152 + (quad * 4 + r) * 72 + ni * 16 + r16] =
            (__bf16)__builtin_amdgcn_exp2f(sv);
      }

#pragma unroll
    for (int ks = 0; ks < 2; ++ks) {
      bf16x8 ap = *reinterpret_cast<const bf16x8*>(
          &Ps[w * 1152 + r16 * 72 + ks * 32 + quad * 8]);
#pragma unroll
      for (int ni = 0; ni < 5; ++ni) {
        int row = ni * 16 + r16;
        bf16x8 bv = *reinterpret_cast<const bf16x8*>(
            &Vt[cur][row * 64 + (((ks << 2) | quad) ^ (r16 & 7)) * 8]);
        O[ni] = __builtin_amdgcn_mfma_f32_16x16x32_bf16(ap, bv, O[ni], 0, 0, 0);
      }
    }
  }

  float invl[4];
#pragma unroll
  for (int r = 0; r < 4; ++r) {
    float l = __shfl(O[4][r], lane & 48);
    invl[r] = 1.f / l;
  }
#pragma unroll
  for (int r = 0; r < 4; ++r) {
    int qrow = q0 + w * 16 + quad * 4 + r;
    __bf16* op = ctx + ((size_t)(b * Tt + qrow)) * Dm + h * HD;
#pragma unroll
    for (int ni = 0; ni < 4; ++ni)
      op[ni * 16 + r16] = (__bf16)(O[ni][r] * invl[r]);
  }
}

extern "C" void kernel_launch(void* const* d_in, const int* in_sizes, int n_in,
                              void* d_out, int out_size, void* d_ws, size_t ws_size,
                              hipStream_t stream) {
  const float* x = (const float*)d_in[0];
  const float* wq = (const float*)d_in[1];
  const float* wk = (const float*)d_in[2];
  const float* wv = (const float*)d_in[3];
  const float* wo = (const float*)d_in[4];
  const float* bo = (const float*)d_in[5];
  const float* w1 = (const float*)d_in[6];
  const float* b1 = (const float*)d_in[7];
  const float* w2 = (const float*)d_in[8];
  const float* b2 = (const float*)d_in[9];
  const float* a1 = (const float*)d_in[10];
  const float* s1 = (const float*)d_in[11];
  const float* a2 = (const float*)d_in[12];
  const float* s2 = (const float*)d_in[13];
  float* out = (float*)d_out;
  char* ws = (char*)d_ws;

  const size_t MB = 1024 * 1024;
  __hip_bfloat16* WqkvT = (__hip_bfloat16*)(ws + 0 * MB);  // 6MB: WqT|WkT|WvT
  __hip_bfloat16* WkT = (__hip_bfloat16*)(ws + 2 * MB);
  __hip_bfloat16* WvT = (__hip_bfloat16*)(ws + 4 * MB);
  __hip_bfloat16* WoT = (__hip_bfloat16*)(ws + 6 * MB);
  __hip_bfloat16* W1T = (__hip_bfloat16*)(ws + 8 * MB);
  __hip_bfloat16* W2T = (__hip_bfloat16*)(ws + 16 * MB);
  __hip_bfloat16* h1  = (__hip_bfloat16*)(ws + 24 * MB);
  __hip_bfloat16* qkvb = (__hip_bfloat16*)(ws + 32 * MB);  // 24MB: q|k|v head-major
  __hip_bfloat16* ctxb = (__hip_bfloat16*)(ws + 56 * MB);  // token-major
  __hip_bfloat16* h2  = (__hip_bfloat16*)(ws + 64 * MB);
  __hip_bfloat16* g   = (__hip_bfloat16*)(ws + 72 * MB);   // 32MB
  __hip_bfloat16* vtb = (__hip_bfloat16*)(ws + 104 * MB);  // 8MB: V^T [B*H,64,T]

  dim3 tb(32, 8);
  transpose_bf16_kernel<<<dim3(Dm / 32, Dm / 32), tb, 0, stream>>>(wq, WqkvT, Dm, Dm);
  transpose_bf16_kernel<<<dim3(Dm / 32, Dm / 32), tb, 0, stream>>>(wk, WkT, Dm, Dm);
  transpose_bf16_kernel<<<dim3(Dm / 32, Dm / 32), tb, 0, stream>>>(wv, WvT, Dm, Dm);
  transpose_bf16_kernel<<<dim3(Dm / 32, Dm / 32), tb, 0, stream>>>(wo, WoT, Dm, Dm);
  transpose_bf16_kernel<<<dim3(FF / 32, Dm / 32), tb, 0, stream>>>(w1, W1T, Dm, FF);
  transpose_bf16_kernel<<<dim3(Dm / 32, FF / 32), tb, 0, stream>>>(w2, W2T, FF, Dm);

  ln_bf16_kernel<<<MR, 256, 0, stream>>>(x, a1, s1, h1);

  gemm_tiled<3><<<dim3(3 * Dm / 128, MR / 128), 256, 0, stream>>>(
      (const __bf16*)h1, (const __bf16*)WqkvT, qkvb, nullptr, nullptr, MR, 3 * Dm, Dm);

  vtrans_kernel<<<dim3(Bb * Hh, Tt / 64), 256, 0, stream>>>(
      (const __bf16*)(qkvb + 2 * (size_t)MR * Dm), (__bf16*)vtb);

  attn_kernel<<<dim3(Bb * Hh, Tt / 64), 256, 0, stream>>>(
      (const __bf16*)qkvb, (const __bf16*)(qkvb + (size_t)MR * Dm),
      (const __bf16*)vtb, (__bf16*)ctxb);

  // x2 = ctx @ Wo + bo + x
  gemm_tiled64<<<dim3(Dm / 128, MR / 64), 256, 0, stream>>>(
      (const __bf16*)ctxb, (const __bf16*)WoT, out, bo, x, MR, Dm, Dm);

  ln_bf16_kernel<<<MR, 256, 0, stream>>>(out, a2, s2, h2);

  gemm_tiled<2><<<dim3(FF / 128, MR / 128), 256, 0, stream>>>(
      (const __bf16*)h2, (const __bf16*)W1T, g, b1, nullptr, MR, FF, Dm);

  // out = g @ W2 + b2 + x2
  gemm_tiled64<<<dim3(Dm / 128, MR / 64), 256, 0, stream>>>(
      (const __bf16*)g, (const __bf16*)W2T, out, b2, out, MR, Dm, FF);
}